// Round 2
// baseline (1326.955 us; speedup 1.0000x reference)
//
#include <hip/hip_runtime.h>
#include <hip/hip_bf16.h>
#include <math.h>

#define N_NODES 16384
#define N_EDGES 131072
#define INV_SQRT3 0.57735026918962576451f
#define INV_SQRT2 0.70710678118654752440f
#define LN_EPS 1e-5f

__device__ __forceinline__ float wave_sum(float v) {
    #pragma unroll
    for (int off = 32; off > 0; off >>= 1) v += __shfl_xor(v, off, 64);
    return v;
}

// One wave per edge. Lane u handles channel u (and u+64 where mul=128).
// Accumulates straight into the output buffer (same shape as agg).
__global__ __launch_bounds__(256) void tp_scatter_kernel(
    const float* __restrict__ nf,    // (N,320)
    const float* __restrict__ sh,    // (E,4)
    const float* __restrict__ w,     // (E,448)
    const float* __restrict__ bias,  // (192,)
    const int*   __restrict__ esrc,
    const int*   __restrict__ edst,
    float* __restrict__ agg)         // (N,960) == d_out
{
    const int e = blockIdx.x * 4 + (threadIdx.x >> 6);
    const int u = threadIdx.x & 63;
    if (e >= N_EDGES) return;

    const float4 s4 = ((const float4*)sh)[e];   // ys, yv0, yv1, yv2
    const float ys = s4.x, yv0 = s4.y, yv1 = s4.z, yv2 = s4.w;

    const int src = esrc[e];
    const int dst = edst[e];
    const float* __restrict__ x  = nf + (size_t)src * 320;
    const float* __restrict__ we = w  + (size_t)e   * 448;

    // inputs for this lane
    const float xs0 = x[u];
    const float xs1 = x[64 + u];
    const float a0  = x[128 + u * 3 + 0];
    const float a1  = x[128 + u * 3 + 1];
    const float a2  = x[128 + u * 3 + 2];

    const float w0a = we[u],        w0b = we[64 + u];
    const float w1a = we[128 + u],  w1b = we[192 + u];
    const float w2  = we[256 + u];
    const float w3  = we[320 + u];
    const float w4  = we[384 + u];

    float* __restrict__ o = agg + (size_t)dst * 960;

    // out0a (channels u, u+64) + bias
    atomicAdd(&o[u],        w0a * xs0 * ys + bias[u]);
    atomicAdd(&o[64 + u],   w0b * xs1 * ys + bias[64 + u]);

    // out0b (channel u) + bias
    const float dot = a0 * yv0 + a1 * yv1 + a2 * yv2;
    atomicAdd(&o[128 + u],  w3 * dot * INV_SQRT3 + bias[128 + u]);

    // out1a: (w1*xs)[c] * yv[d], channels u and u+64
    const float p0 = w1a * xs0;
    const float p1 = w1b * xs1;
    atomicAdd(&o[192 + u * 3 + 0], p0 * yv0);
    atomicAdd(&o[192 + u * 3 + 1], p0 * yv1);
    atomicAdd(&o[192 + u * 3 + 2], p0 * yv2);
    atomicAdd(&o[192 + (64 + u) * 3 + 0], p1 * yv0);
    atomicAdd(&o[192 + (64 + u) * 3 + 1], p1 * yv1);
    atomicAdd(&o[192 + (64 + u) * 3 + 2], p1 * yv2);

    // out1b: (w2*ys) * xv
    const float q = w2 * ys;
    atomicAdd(&o[576 + u * 3 + 0], q * a0);
    atomicAdd(&o[576 + u * 3 + 1], q * a1);
    atomicAdd(&o[576 + u * 3 + 2], q * a2);

    // out1c: w4 * cross(xv, yv) * INV_SQRT2
    const float r  = w4 * INV_SQRT2;
    const float c0 = a1 * yv2 - a2 * yv1;
    const float c1 = a2 * yv0 - a0 * yv2;
    const float c2 = a0 * yv1 - a1 * yv0;
    atomicAdd(&o[768 + u * 3 + 0], r * c0);
    atomicAdd(&o[768 + u * 3 + 1], r * c1);
    atomicAdd(&o[768 + u * 3 + 2], r * c2);
}

// One wave per node: equivariant LayerNorm IN-PLACE over fields
// [(128,0),(64,0),(128,1),(64,1),(64,1)] laid out as 128+64+384+192+192 = 960.
__global__ __launch_bounds__(256) void eq_layernorm_kernel(
    float* __restrict__ buf,         // (N,960): read agg, write normalized
    const float* __restrict__ lnw,   // (448,)
    const float* __restrict__ lnb)   // (192,)
{
    const int n = blockIdx.x * 4 + (threadIdx.x >> 6);
    const int u = threadIdx.x & 63;
    if (n >= N_NODES) return;

    float* __restrict__ a = buf + (size_t)n * 960;

    // ---- Field 0: mul=128, l=0 ----
    {
        const float x0 = a[u];
        const float x1 = a[64 + u];
        const float s   = wave_sum(x0 + x1);
        const float ssq = wave_sum(x0 * x0 + x1 * x1);
        const float mean = s * (1.0f / 128.0f);
        const float var  = ssq * (1.0f / 128.0f) - mean * mean;
        const float fn   = rsqrtf(var + LN_EPS);
        a[u]      = (x0 - mean) * fn * lnw[u]      + lnb[u];
        a[64 + u] = (x1 - mean) * fn * lnw[64 + u] + lnb[64 + u];
    }
    // ---- Field 1: mul=64, l=0 ----
    {
        const float y = a[128 + u];
        const float s   = wave_sum(y);
        const float ssq = wave_sum(y * y);
        const float mean = s * (1.0f / 64.0f);
        const float var  = ssq * (1.0f / 64.0f) - mean * mean;
        const float fn   = rsqrtf(var + LN_EPS);
        a[128 + u] = (y - mean) * fn * lnw[128 + u] + lnb[128 + u];
    }
    // ---- Field 2: mul=128, l=1 (384 elems at 192) ----
    {
        float v[6];
        float acc = 0.0f;
        #pragma unroll
        for (int k = 0; k < 6; ++k) {
            v[k] = a[192 + k * 64 + u];
            acc += v[k] * v[k];
        }
        const float ssq  = wave_sum(acc);
        const float norm = ssq * (1.0f / 384.0f);
        const float fn0  = rsqrtf(norm + LN_EPS);
        #pragma unroll
        for (int k = 0; k < 6; ++k) {
            const int idx = k * 64 + u;
            const int c   = idx / 3;
            a[192 + idx] = v[k] * fn0 * lnw[192 + c];
        }
    }
    // ---- Field 3: mul=64, l=1 (192 elems at 576) ----
    {
        float v[3];
        float acc = 0.0f;
        #pragma unroll
        for (int k = 0; k < 3; ++k) {
            v[k] = a[576 + k * 64 + u];
            acc += v[k] * v[k];
        }
        const float ssq  = wave_sum(acc);
        const float norm = ssq * (1.0f / 192.0f);
        const float fn0  = rsqrtf(norm + LN_EPS);
        #pragma unroll
        for (int k = 0; k < 3; ++k) {
            const int idx = k * 64 + u;
            const int c   = idx / 3;
            a[576 + idx] = v[k] * fn0 * lnw[320 + c];
        }
    }
    // ---- Field 4: mul=64, l=1 (192 elems at 768) ----
    {
        float v[3];
        float acc = 0.0f;
        #pragma unroll
        for (int k = 0; k < 3; ++k) {
            v[k] = a[768 + k * 64 + u];
            acc += v[k] * v[k];
        }
        const float ssq  = wave_sum(acc);
        const float norm = ssq * (1.0f / 192.0f);
        const float fn0  = rsqrtf(norm + LN_EPS);
        #pragma unroll
        for (int k = 0; k < 3; ++k) {
            const int idx = k * 64 + u;
            const int c   = idx / 3;
            a[768 + idx] = v[k] * fn0 * lnw[384 + c];
        }
    }
}

extern "C" void kernel_launch(void* const* d_in, const int* in_sizes, int n_in,
                              void* d_out, int out_size, void* d_ws, size_t ws_size,
                              hipStream_t stream) {
    const float* node_feat   = (const float*)d_in[0];
    const float* edge_sh     = (const float*)d_in[1];
    const float* edge_weight = (const float*)d_in[2];
    const float* tp_bias     = (const float*)d_in[3];
    const float* ln_weight   = (const float*)d_in[4];
    const float* ln_bias     = (const float*)d_in[5];
    const int*   edge_src    = (const int*)d_in[6];
    const int*   edge_dst    = (const int*)d_in[7];
    float* out = (float*)d_out;   // (N_NODES, 960) — used as the accumulator too

    const size_t out_bytes = (size_t)N_NODES * 960 * sizeof(float);
    hipMemsetAsync(out, 0, out_bytes, stream);

    // 4 edges per 256-thread block (one wave each)
    tp_scatter_kernel<<<N_EDGES / 4, 256, 0, stream>>>(
        node_feat, edge_sh, edge_weight, tp_bias, edge_src, edge_dst, out);

    // 4 nodes per 256-thread block (one wave each), LN in-place on out
    eq_layernorm_kernel<<<N_NODES / 4, 256, 0, stream>>>(
        out, ln_weight, ln_bias);
}

// Round 3
// 401.383 us; speedup vs baseline: 3.3060x; 3.3060x over previous
//
#include <hip/hip_runtime.h>
#include <hip/hip_bf16.h>
#include <math.h>

#define N_NODES 16384
#define N_EDGES 131072
#define INV_SQRT3 0.57735026918962576451f
#define INV_SQRT2 0.70710678118654752440f
#define LN_EPS 1e-5f

__device__ __forceinline__ float wave_sum(float v) {
    #pragma unroll
    for (int off = 32; off > 0; off >>= 1) v += __shfl_xor(v, off, 64);
    return v;
}

// ---------------- CSR build ----------------

__global__ __launch_bounds__(256) void hist_kernel(
    const int* __restrict__ edst, int* __restrict__ counts)
{
    const int e = blockIdx.x * 256 + threadIdx.x;
    if (e < N_EDGES) atomicAdd(&counts[edst[e]], 1);
}

// Single block, 1024 threads, 16 counters each: exclusive scan -> row_ptr, cursor.
__global__ __launch_bounds__(1024) void scan_kernel(
    const int* __restrict__ counts, int* __restrict__ row_ptr,
    int* __restrict__ cursor)
{
    __shared__ int lds[1024];
    const int t = threadIdx.x;
    const int base = t * 16;
    int local[16];
    int sum = 0;
    #pragma unroll
    for (int i = 0; i < 16; ++i) { local[i] = counts[base + i]; sum += local[i]; }
    lds[t] = sum;
    __syncthreads();
    for (int off = 1; off < 1024; off <<= 1) {
        int v = (t >= off) ? lds[t - off] : 0;
        __syncthreads();
        lds[t] += v;
        __syncthreads();
    }
    int run = (t == 0) ? 0 : lds[t - 1];
    #pragma unroll
    for (int i = 0; i < 16; ++i) {
        row_ptr[base + i] = run;
        cursor[base + i]  = run;
        run += local[i];
    }
    if (t == 1023) row_ptr[N_NODES] = run;   // == N_EDGES
}

__global__ __launch_bounds__(256) void fill_kernel(
    const int* __restrict__ edst, int* __restrict__ cursor,
    int* __restrict__ edge_ids)
{
    const int e = blockIdx.x * 256 + threadIdx.x;
    if (e < N_EDGES) {
        const int pos = atomicAdd(&cursor[edst[e]], 1);
        edge_ids[pos] = e;
    }
}

// ---------------- Fused gather + depthwise TP + bias + equivariant LN ----------------
// One wave per node. Lane u owns channels u and u+64 (for mul=128 fields)
// and channel u (for mul=64 fields). All 960 outputs accumulated in registers.
__global__ __launch_bounds__(256) void gather_tp_ln_kernel(
    const float* __restrict__ nf,     // (N,320)
    const float* __restrict__ sh,     // (E,4)
    const float* __restrict__ w,      // (E,448)
    const float* __restrict__ bias,   // (192,)
    const int*   __restrict__ esrc,   // (E,)
    const int*   __restrict__ row_ptr,// (N+1,)
    const int*   __restrict__ edge_ids,// (E,)
    const float* __restrict__ lnw,    // (448,)
    const float* __restrict__ lnb,    // (192,)
    float* __restrict__ out)          // (N,960)
{
    const int n = blockIdx.x * 4 + (threadIdx.x >> 6);
    const int u = threadIdx.x & 63;
    if (n >= N_NODES) return;

    const int start = row_ptr[n];
    const int end   = row_ptr[n + 1];

    float o0a0 = 0.f, o0a1 = 0.f, o0b = 0.f;
    float o1a0x = 0.f, o1a0y = 0.f, o1a0z = 0.f;   // field2, channel u
    float o1a1x = 0.f, o1a1y = 0.f, o1a1z = 0.f;   // field2, channel 64+u
    float o1bx = 0.f, o1by = 0.f, o1bz = 0.f;      // field3
    float o1cx = 0.f, o1cy = 0.f, o1cz = 0.f;      // field4

    for (int j = start; j < end; ++j) {
        const int e = edge_ids[j];                 // wave-uniform
        const float4 s4 = ((const float4*)sh)[e];
        const float ys = s4.x, yv0 = s4.y, yv1 = s4.z, yv2 = s4.w;
        const int src = esrc[e];

        const float* __restrict__ x  = nf + (size_t)src * 320;
        const float* __restrict__ we = w  + (size_t)e   * 448;

        const float xs0 = x[u];
        const float xs1 = x[64 + u];
        const float a0  = x[128 + u * 3 + 0];
        const float a1  = x[128 + u * 3 + 1];
        const float a2  = x[128 + u * 3 + 2];

        const float w0a = we[u],       w0b = we[64 + u];
        const float w1a = we[128 + u], w1b = we[192 + u];
        const float w2  = we[256 + u];
        const float w3  = we[320 + u];
        const float w4  = we[384 + u];

        // out0a
        o0a0 += w0a * xs0 * ys;
        o0a1 += w0b * xs1 * ys;
        // out0b
        o0b  += w3 * (a0 * yv0 + a1 * yv1 + a2 * yv2) * INV_SQRT3;
        // out1a
        const float p0 = w1a * xs0;
        const float p1 = w1b * xs1;
        o1a0x += p0 * yv0; o1a0y += p0 * yv1; o1a0z += p0 * yv2;
        o1a1x += p1 * yv0; o1a1y += p1 * yv1; o1a1z += p1 * yv2;
        // out1b
        const float q = w2 * ys;
        o1bx += q * a0; o1by += q * a1; o1bz += q * a2;
        // out1c
        const float r = w4 * INV_SQRT2;
        o1cx += r * (a1 * yv2 - a2 * yv1);
        o1cy += r * (a2 * yv0 - a0 * yv2);
        o1cz += r * (a0 * yv1 - a1 * yv0);
    }

    // bias accumulated once per edge -> degree * bias
    const float deg = (float)(end - start);
    o0a0 += deg * bias[u];
    o0a1 += deg * bias[64 + u];
    o0b  += deg * bias[128 + u];

    float* __restrict__ o = out + (size_t)n * 960;

    // ---- Field 0: mul=128, l=0 (channels u, 64+u) ----
    {
        const float s    = wave_sum(o0a0 + o0a1);
        const float ssq  = wave_sum(o0a0 * o0a0 + o0a1 * o0a1);
        const float mean = s * (1.0f / 128.0f);
        const float var  = ssq * (1.0f / 128.0f) - mean * mean;
        const float fn   = rsqrtf(var + LN_EPS);
        o[u]      = (o0a0 - mean) * fn * lnw[u]      + lnb[u];
        o[64 + u] = (o0a1 - mean) * fn * lnw[64 + u] + lnb[64 + u];
    }
    // ---- Field 1: mul=64, l=0 ----
    {
        const float s    = wave_sum(o0b);
        const float ssq  = wave_sum(o0b * o0b);
        const float mean = s * (1.0f / 64.0f);
        const float var  = ssq * (1.0f / 64.0f) - mean * mean;
        const float fn   = rsqrtf(var + LN_EPS);
        o[128 + u] = (o0b - mean) * fn * lnw[128 + u] + lnb[128 + u];
    }
    // ---- Field 2: mul=128, l=1 ----
    {
        const float ssq = wave_sum(o1a0x*o1a0x + o1a0y*o1a0y + o1a0z*o1a0z +
                                   o1a1x*o1a1x + o1a1y*o1a1y + o1a1z*o1a1z);
        const float fn  = rsqrtf(ssq * (1.0f / 384.0f) + LN_EPS);
        const float g0  = fn * lnw[192 + u];
        const float g1  = fn * lnw[256 + u];
        o[192 + u * 3 + 0] = o1a0x * g0;
        o[192 + u * 3 + 1] = o1a0y * g0;
        o[192 + u * 3 + 2] = o1a0z * g0;
        o[192 + (64 + u) * 3 + 0] = o1a1x * g1;
        o[192 + (64 + u) * 3 + 1] = o1a1y * g1;
        o[192 + (64 + u) * 3 + 2] = o1a1z * g1;
    }
    // ---- Field 3: mul=64, l=1 ----
    {
        const float ssq = wave_sum(o1bx*o1bx + o1by*o1by + o1bz*o1bz);
        const float fn  = rsqrtf(ssq * (1.0f / 192.0f) + LN_EPS);
        const float g   = fn * lnw[320 + u];
        o[576 + u * 3 + 0] = o1bx * g;
        o[576 + u * 3 + 1] = o1by * g;
        o[576 + u * 3 + 2] = o1bz * g;
    }
    // ---- Field 4: mul=64, l=1 ----
    {
        const float ssq = wave_sum(o1cx*o1cx + o1cy*o1cy + o1cz*o1cz);
        const float fn  = rsqrtf(ssq * (1.0f / 192.0f) + LN_EPS);
        const float g   = fn * lnw[384 + u];
        o[768 + u * 3 + 0] = o1cx * g;
        o[768 + u * 3 + 1] = o1cy * g;
        o[768 + u * 3 + 2] = o1cz * g;
    }
}

extern "C" void kernel_launch(void* const* d_in, const int* in_sizes, int n_in,
                              void* d_out, int out_size, void* d_ws, size_t ws_size,
                              hipStream_t stream) {
    const float* node_feat   = (const float*)d_in[0];
    const float* edge_sh     = (const float*)d_in[1];
    const float* edge_weight = (const float*)d_in[2];
    const float* tp_bias     = (const float*)d_in[3];
    const float* ln_weight   = (const float*)d_in[4];
    const float* ln_bias     = (const float*)d_in[5];
    const int*   edge_src    = (const int*)d_in[6];
    const int*   edge_dst    = (const int*)d_in[7];
    float* out = (float*)d_out;

    // workspace layout (ints): counts[16384] | row_ptr[16385] | cursor[16384] | edge_ids[131072]
    int* counts   = (int*)d_ws;
    int* row_ptr  = counts + N_NODES;
    int* cursor   = row_ptr + (N_NODES + 1);
    int* edge_ids = cursor + N_NODES;

    hipMemsetAsync(counts, 0, (size_t)N_NODES * sizeof(int), stream);

    hist_kernel<<<N_EDGES / 256, 256, 0, stream>>>(edge_dst, counts);
    scan_kernel<<<1, 1024, 0, stream>>>(counts, row_ptr, cursor);
    fill_kernel<<<N_EDGES / 256, 256, 0, stream>>>(edge_dst, cursor, edge_ids);

    gather_tp_ln_kernel<<<N_NODES / 4, 256, 0, stream>>>(
        node_feat, edge_sh, edge_weight, tp_bias, edge_src,
        row_ptr, edge_ids, ln_weight, ln_bias, out);
}

// Round 4
// 383.103 us; speedup vs baseline: 3.4637x; 1.0477x over previous
//
#include <hip/hip_runtime.h>
#include <hip/hip_bf16.h>
#include <math.h>

#define N_NODES 16384
#define N_EDGES 131072
#define INV_SQRT3 0.57735026918962576451f
#define INV_SQRT2 0.70710678118654752440f
#define LN_EPS 1e-5f

__device__ __forceinline__ float wave_sum(float v) {
    #pragma unroll
    for (int off = 32; off > 0; off >>= 1) v += __shfl_xor(v, off, 64);
    return v;
}

// ---------------- CSR build ----------------

__global__ __launch_bounds__(256) void hist_kernel(
    const int* __restrict__ edst, int* __restrict__ counts)
{
    const int e = blockIdx.x * 256 + threadIdx.x;
    if (e < N_EDGES) atomicAdd(&counts[edst[e]], 1);
}

// Single block, 1024 threads, 16 counters each: exclusive scan -> row_ptr, cursor.
__global__ __launch_bounds__(1024) void scan_kernel(
    const int* __restrict__ counts, int* __restrict__ row_ptr,
    int* __restrict__ cursor)
{
    __shared__ int lds[1024];
    const int t = threadIdx.x;
    const int base = t * 16;
    int local[16];
    int sum = 0;
    #pragma unroll
    for (int i = 0; i < 16; ++i) { local[i] = counts[base + i]; sum += local[i]; }
    lds[t] = sum;
    __syncthreads();
    for (int off = 1; off < 1024; off <<= 1) {
        int v = (t >= off) ? lds[t - off] : 0;
        __syncthreads();
        lds[t] += v;
        __syncthreads();
    }
    int run = (t == 0) ? 0 : lds[t - 1];
    #pragma unroll
    for (int i = 0; i < 16; ++i) {
        row_ptr[base + i] = run;
        cursor[base + i]  = run;
        run += local[i];
    }
    if (t == 1023) row_ptr[N_NODES] = run;   // == N_EDGES
}

// Store (edge_id, src) pairs so the hot loop has one fewer dependent load level.
__global__ __launch_bounds__(256) void fill_kernel(
    const int* __restrict__ edst, const int* __restrict__ esrc,
    int* __restrict__ cursor, int2* __restrict__ pairs)
{
    const int e = blockIdx.x * 256 + threadIdx.x;
    if (e < N_EDGES) {
        const int pos = atomicAdd(&cursor[edst[e]], 1);
        pairs[pos] = make_int2(e, esrc[e]);
    }
}

// ---------------- Fused gather + depthwise TP + bias + equivariant LN ----------------
// One wave per node. Lane u owns channels u and u+64 (mul=128 fields), channel u
// (mul=64 fields). All 960 outputs live in registers; output row written once.
__global__ __launch_bounds__(256) void gather_tp_ln_kernel(
    const float* __restrict__ nf,     // (N,320)
    const float* __restrict__ sh,     // (E,4)
    const float* __restrict__ w,      // (E,448)
    const float* __restrict__ bias,   // (192,)
    const int*   __restrict__ row_ptr,// (N+1,)
    const int2*  __restrict__ pairs,  // (E,) (edge_id, src)
    const float* __restrict__ lnw,    // (448,)
    const float* __restrict__ lnb,    // (192,)
    float* __restrict__ out)          // (N,960)
{
    const int n = blockIdx.x * 4 + (threadIdx.x >> 6);
    const int u = threadIdx.x & 63;
    if (n >= N_NODES) return;

    const int start = row_ptr[n];
    const int end   = row_ptr[n + 1];

    float o0a0 = 0.f, o0a1 = 0.f, o0b = 0.f;
    float o1a0x = 0.f, o1a0y = 0.f, o1a0z = 0.f;   // field2, channel u
    float o1a1x = 0.f, o1a1y = 0.f, o1a1z = 0.f;   // field2, channel 64+u
    float o1bx = 0.f, o1by = 0.f, o1bz = 0.f;      // field3
    float o1cx = 0.f, o1cy = 0.f, o1cz = 0.f;      // field4

    int2 pr = (start < end) ? pairs[start] : make_int2(0, 0);

    for (int j = start; j < end; ++j) {
        const int2 cur = pr;
        if (j + 1 < end) pr = pairs[j + 1];          // prefetch next pair

        // wave-uniform -> force into SGPRs (scalar base addressing)
        const int e   = __builtin_amdgcn_readfirstlane(cur.x);
        const int src = __builtin_amdgcn_readfirstlane(cur.y);

        const float4 s4 = *(const float4*)(sh + 4 * (size_t)e);
        const float ys = s4.x, yv0 = s4.y, yv1 = s4.z, yv2 = s4.w;

        const float* __restrict__ x  = nf + (size_t)src * 320;
        const float* __restrict__ we = w  + (size_t)e   * 448;

        const float xs0 = x[u];
        const float xs1 = x[64 + u];
        const float a0  = x[128 + u * 3 + 0];
        const float a1  = x[128 + u * 3 + 1];
        const float a2  = x[128 + u * 3 + 2];

        // edge_weight streams once (235 MB): non-temporal so it doesn't
        // evict the node_feat working set (21 MB, reused ~8x) from L2.
        const float w0a = __builtin_nontemporal_load(&we[u]);
        const float w0b = __builtin_nontemporal_load(&we[64 + u]);
        const float w1a = __builtin_nontemporal_load(&we[128 + u]);
        const float w1b = __builtin_nontemporal_load(&we[192 + u]);
        const float w2  = __builtin_nontemporal_load(&we[256 + u]);
        const float w3  = __builtin_nontemporal_load(&we[320 + u]);
        const float w4  = __builtin_nontemporal_load(&we[384 + u]);

        // out0a
        o0a0 += w0a * xs0 * ys;
        o0a1 += w0b * xs1 * ys;
        // out0b
        o0b  += w3 * (a0 * yv0 + a1 * yv1 + a2 * yv2) * INV_SQRT3;
        // out1a
        const float p0 = w1a * xs0;
        const float p1 = w1b * xs1;
        o1a0x += p0 * yv0; o1a0y += p0 * yv1; o1a0z += p0 * yv2;
        o1a1x += p1 * yv0; o1a1y += p1 * yv1; o1a1z += p1 * yv2;
        // out1b
        const float q = w2 * ys;
        o1bx += q * a0; o1by += q * a1; o1bz += q * a2;
        // out1c
        const float r = w4 * INV_SQRT2;
        o1cx += r * (a1 * yv2 - a2 * yv1);
        o1cy += r * (a2 * yv0 - a0 * yv2);
        o1cz += r * (a0 * yv1 - a1 * yv0);
    }

    // bias accumulated once per edge -> degree * bias
    const float deg = (float)(end - start);
    o0a0 += deg * bias[u];
    o0a1 += deg * bias[64 + u];
    o0b  += deg * bias[128 + u];

    float* __restrict__ o = out + (size_t)n * 960;

    // ---- Field 0: mul=128, l=0 ----
    {
        const float s    = wave_sum(o0a0 + o0a1);
        const float ssq  = wave_sum(o0a0 * o0a0 + o0a1 * o0a1);
        const float mean = s * (1.0f / 128.0f);
        const float var  = ssq * (1.0f / 128.0f) - mean * mean;
        const float fn   = rsqrtf(var + LN_EPS);
        o[u]      = (o0a0 - mean) * fn * lnw[u]      + lnb[u];
        o[64 + u] = (o0a1 - mean) * fn * lnw[64 + u] + lnb[64 + u];
    }
    // ---- Field 1: mul=64, l=0 ----
    {
        const float s    = wave_sum(o0b);
        const float ssq  = wave_sum(o0b * o0b);
        const float mean = s * (1.0f / 64.0f);
        const float var  = ssq * (1.0f / 64.0f) - mean * mean;
        const float fn   = rsqrtf(var + LN_EPS);
        o[128 + u] = (o0b - mean) * fn * lnw[128 + u] + lnb[128 + u];
    }
    // ---- Field 2: mul=128, l=1 ----
    {
        const float ssq = wave_sum(o1a0x*o1a0x + o1a0y*o1a0y + o1a0z*o1a0z +
                                   o1a1x*o1a1x + o1a1y*o1a1y + o1a1z*o1a1z);
        const float fn  = rsqrtf(ssq * (1.0f / 384.0f) + LN_EPS);
        const float g0  = fn * lnw[192 + u];
        const float g1  = fn * lnw[256 + u];
        o[192 + u * 3 + 0] = o1a0x * g0;
        o[192 + u * 3 + 1] = o1a0y * g0;
        o[192 + u * 3 + 2] = o1a0z * g0;
        o[192 + (64 + u) * 3 + 0] = o1a1x * g1;
        o[192 + (64 + u) * 3 + 1] = o1a1y * g1;
        o[192 + (64 + u) * 3 + 2] = o1a1z * g1;
    }
    // ---- Field 3: mul=64, l=1 ----
    {
        const float ssq = wave_sum(o1bx*o1bx + o1by*o1by + o1bz*o1bz);
        const float fn  = rsqrtf(ssq * (1.0f / 192.0f) + LN_EPS);
        const float g   = fn * lnw[320 + u];
        o[576 + u * 3 + 0] = o1bx * g;
        o[576 + u * 3 + 1] = o1by * g;
        o[576 + u * 3 + 2] = o1bz * g;
    }
    // ---- Field 4: mul=64, l=1 ----
    {
        const float ssq = wave_sum(o1cx*o1cx + o1cy*o1cy + o1cz*o1cz);
        const float fn  = rsqrtf(ssq * (1.0f / 192.0f) + LN_EPS);
        const float g   = fn * lnw[384 + u];
        o[768 + u * 3 + 0] = o1cx * g;
        o[768 + u * 3 + 1] = o1cy * g;
        o[768 + u * 3 + 2] = o1cz * g;
    }
}

extern "C" void kernel_launch(void* const* d_in, const int* in_sizes, int n_in,
                              void* d_out, int out_size, void* d_ws, size_t ws_size,
                              hipStream_t stream) {
    const float* node_feat   = (const float*)d_in[0];
    const float* edge_sh     = (const float*)d_in[1];
    const float* edge_weight = (const float*)d_in[2];
    const float* tp_bias     = (const float*)d_in[3];
    const float* ln_weight   = (const float*)d_in[4];
    const float* ln_bias     = (const float*)d_in[5];
    const int*   edge_src    = (const int*)d_in[6];
    const int*   edge_dst    = (const int*)d_in[7];
    float* out = (float*)d_out;

    // workspace (ints): counts[16384] | row_ptr[16385] | cursor[16384] | pad | pairs[131072 int2]
    int* counts   = (int*)d_ws;
    int* row_ptr  = counts + N_NODES;
    int* cursor   = row_ptr + (N_NODES + 1);
    int2* pairs   = (int2*)(cursor + N_NODES + 1);   // 8B-aligned

    hipMemsetAsync(counts, 0, (size_t)N_NODES * sizeof(int), stream);

    hist_kernel<<<N_EDGES / 256, 256, 0, stream>>>(edge_dst, counts);
    scan_kernel<<<1, 1024, 0, stream>>>(counts, row_ptr, cursor);
    fill_kernel<<<N_EDGES / 256, 256, 0, stream>>>(edge_dst, edge_src, cursor, pairs);

    gather_tp_ln_kernel<<<N_NODES / 4, 256, 0, stream>>>(
        node_feat, edge_sh, edge_weight, tp_bias,
        row_ptr, pairs, ln_weight, ln_bias, out);
}